// Round 4
// baseline (306.217 us; speedup 1.0000x reference)
//
#include <hip/hip_runtime.h>
#include <hip/hip_bf16.h>
#include <math.h>

#define B_ 16
#define D_ 768
#define N_ 1024
#define Z_ 256
#define TOPK_ 512
#define HW_ 32
#define EPS_ 1e-5f

typedef unsigned int uint;
typedef unsigned short ushort;
typedef __attribute__((ext_vector_type(4))) short short4v;
typedef __attribute__((ext_vector_type(8))) short bf16x8;
typedef __attribute__((ext_vector_type(4))) float f32x4;
typedef __attribute__((ext_vector_type(4))) int int4v;

__device__ __forceinline__ ushort f2bf(float v) {
  uint b = __float_as_uint(v);
  b += 0x7FFFu + ((b >> 16) & 1u);
  return (ushort)(b >> 16);
}
__device__ __forceinline__ float bf2f(ushort h) { return __uint_as_float(((uint)h) << 16); }
__device__ __forceinline__ int pk2(ushort a, ushort b) { return (int)((uint)a | ((uint)b << 16)); }

// ---------------- k_zero: zero the logit accumulator (d_ws is re-poisoned every call)
__global__ __launch_bounds__(1024) void k_zero(float* __restrict__ logit) {
  logit[blockIdx.x * 1024 + threadIdx.x] = 0.f;
}

// ---------------- k_db: db[o] = cb[o]+cw[o,:]@bp ; bg[o] = cb[o]+cw[o,:]@mtk  (256 blocks)
__global__ __launch_bounds__(256) void k_db(const float* __restrict__ cw,
                                            const float* __restrict__ cb,
                                            const float* __restrict__ bp,
                                            const float* __restrict__ mtk,
                                            float* __restrict__ db,
                                            float* __restrict__ bg) {
  __shared__ float s1[4], s2[4];
  int o = blockIdx.x, tid = threadIdx.x;
  float c = cw[o * Z_ + tid];
  float a1 = c * bp[tid], a2 = c * mtk[tid];
#pragma unroll
  for (int m = 32; m > 0; m >>= 1) { a1 += __shfl_xor(a1, m, 64); a2 += __shfl_xor(a2, m, 64); }
  if ((tid & 63) == 0) { s1[tid >> 6] = a1; s2[tid >> 6] = a2; }
  __syncthreads();
  if (tid == 0) {
    db[o] = cb[o] + s1[0] + s1[1] + s1[2] + s1[3];
    bg[o] = cb[o] + s2[0] + s2[1] + s2[2] + s2[3];
  }
}

// ---------------- k_cwT: transpose conv_w (256x256) via 32x32 LDS tiles
__global__ __launch_bounds__(256) void k_cwT(const float* __restrict__ cw,
                                             float* __restrict__ cwT) {
  __shared__ float tile[32][33];
  int bx = blockIdx.x & 7, by = blockIdx.x >> 3;
  int tid = threadIdx.x;
#pragma unroll
  for (int it = 0; it < 4; ++it) {
    int idx = it * 256 + tid, r = idx >> 5, c = idx & 31;
    tile[r][c] = cw[(size_t)(by * 32 + r) * Z_ + bx * 32 + c];
  }
  __syncthreads();
#pragma unroll
  for (int it = 0; it < 4; ++it) {
    int idx = it * 256 + tid, r = idx >> 5, c = idx & 31;
    cwT[(size_t)(bx * 32 + r) * Z_ + by * 32 + c] = tile[c][r];
  }
}

// ---------------- k_w1pack: A-fragments of w1^T, hi/lo split bf16 (contiguous k)
__global__ __launch_bounds__(64) void k_w1pack(const float* __restrict__ w1,
                                               short* __restrict__ wA) {
  int lane = threadIdx.x;
  int f = blockIdx.x;             // 48*24 = 1152
  int eg = f / 24, kkg = f % 24;
  int e = eg * 16 + (lane & 15);
  int d0 = kkg * 32 + 8 * (lane >> 4);
  ushort hh[8], ll[8];
#pragma unroll
  for (int j = 0; j < 8; ++j) {
    float v = w1[(size_t)(d0 + j) * D_ + e];
    hh[j] = f2bf(v);
    ll[j] = f2bf(v - bf2f(hh[j]));
  }
  int4v ph = {pk2(hh[0],hh[1]), pk2(hh[2],hh[3]), pk2(hh[4],hh[5]), pk2(hh[6],hh[7])};
  int4v pl = {pk2(ll[0],ll[1]), pk2(ll[2],ll[3]), pk2(ll[4],ll[5]), pk2(ll[6],ll[7])};
  int4v* W = (int4v*)wA;
  W[(size_t)f * 128 + lane] = ph;
  W[(size_t)f * 128 + 64 + lane] = pl;
}

// ---------------- k_mtpA: Mt[d][o] = sum_z wp[d][z]*cwT[z][o], written directly as packed A-frags
// 96 blocks x 256 thr: thread owns o=tid, d = blockIdx*8 .. +7; cwT reads coalesced, wp scalar (SGPR)
__global__ __launch_bounds__(256) void k_mtpA(const float* __restrict__ wp,
                                              const float* __restrict__ cwT,
                                              short* __restrict__ mtA) {
  int o = threadIdx.x;
  int d0 = blockIdx.x * 8;
  int kkg = blockIdx.x >> 2, g = blockIdx.x & 3;
  float acc[8] = {0.f,0.f,0.f,0.f,0.f,0.f,0.f,0.f};
  for (int z = 0; z < Z_; ++z) {
    float c = cwT[(size_t)z * Z_ + o];
#pragma unroll
    for (int j = 0; j < 8; ++j) acc[j] += wp[(size_t)(d0 + j) * Z_ + z] * c;
  }
  int og = o >> 4, lane = (o & 15) + 16 * g;
  int4v p = {pk2(f2bf(acc[0]),f2bf(acc[1])), pk2(f2bf(acc[2]),f2bf(acc[3])),
             pk2(f2bf(acc[4]),f2bf(acc[5])), pk2(f2bf(acc[6]),f2bf(acc[7]))};
  ((int4v*)mtA)[(size_t)(og * 24 + kkg) * 64 + lane] = p;
}

// ---------------- k_stats: per-token mean + rsqrt(var)
__global__ __launch_bounds__(256) void k_stats(const float* __restrict__ xin,
                                               float* __restrict__ rs_out,
                                               float* __restrict__ mu_out) {
  __shared__ float rs[4][64], rs2[4][64];
  int tid = threadIdx.x;
  int b = blockIdx.x >> 4;
  int n = (blockIdx.x & 15) * 64 + (tid & 63);
  int p = tid >> 6;
  float s = 0.f, s2 = 0.f;
  for (int d = p; d < D_; d += 4) {
    float v = xin[((size_t)b * D_ + d) * N_ + n];
    s += v; s2 += v * v;
  }
  rs[p][tid & 63] = s; rs2[p][tid & 63] = s2;
  __syncthreads();
  if (p == 0) {
    float S = rs[0][tid] + rs[1][tid] + rs[2][tid] + rs[3][tid];
    float S2 = rs2[0][tid] + rs2[1][tid] + rs2[2][tid] + rs2[3][tid];
    float m = S * (1.f / D_);
    float var = S2 * (1.f / D_) - m * m;
    mu_out[b * N_ + n] = m;
    rs_out[b * N_ + n] = rsqrtf(var + EPS_);
  }
}

// ---------------- k_score_mfma: partial logits via split-bf16 MFMA, e-split across 2 blocks
// grid 512: tile = bid&255 (b, n0), eh = bid>>8 (paired +-256 -> same XCD). 8 waves x 3 et x 4 tn.
__global__ __launch_bounds__(512, 4) void k_score_mfma(const float* __restrict__ xin,
                                                       const short* __restrict__ wA,
                                                       const float* __restrict__ b1,
                                                       const float* __restrict__ w2,
                                                       float* __restrict__ logit) {
  __shared__ short panH[64 * 128];
  __shared__ short panL[64 * 128];
  __shared__ float red[8][4][16];
  int tid = threadIdx.x;
  int wave = tid >> 6, lane = tid & 63;
  int g = lane >> 4, cc = lane & 15;
  int tile = blockIdx.x & 255, eh = blockIdx.x >> 8;
  int b = tile >> 4;
  int n0 = (tile & 15) * 64;
  const float* xb = xin + (size_t)b * D_ * N_ + n0;
  int qt = tid & 15, qd = tid >> 4;
  int t0 = qt * 4, dl0 = qd * 4;
  f32x4 acc[3][4];
#pragma unroll
  for (int et = 0; et < 3; ++et)
#pragma unroll
    for (int tn = 0; tn < 4; ++tn) acc[et][tn] = (f32x4){0.f,0.f,0.f,0.f};
  const int4v* Ab = (const int4v*)wA;
  int eg0 = eh * 24 + wave * 3;
  for (int kc = 0; kc < 6; ++kc) {
    float4 v0 = *(const float4*)(xb + (size_t)(kc*128 + dl0 + 0) * N_ + t0);
    float4 v1 = *(const float4*)(xb + (size_t)(kc*128 + dl0 + 1) * N_ + t0);
    float4 v2 = *(const float4*)(xb + (size_t)(kc*128 + dl0 + 2) * N_ + t0);
    float4 v3 = *(const float4*)(xb + (size_t)(kc*128 + dl0 + 3) * N_ + t0);
    __syncthreads();   // previous chunk's compute done before overwrite
#define STG(j, e0, e1, e2, e3) { \
    int t = t0 + (j); \
    int g1 = ((t & 7) ^ (t >> 3)); \
    int sb = t * 128 + (dl0 ^ (g1 << 3)); \
    ushort h0 = f2bf(e0), h1 = f2bf(e1), h2 = f2bf(e2), h3 = f2bf(e3); \
    short4v ph = {(short)h0,(short)h1,(short)h2,(short)h3}; \
    short4v pl = {(short)f2bf((e0)-bf2f(h0)), (short)f2bf((e1)-bf2f(h1)), \
                  (short)f2bf((e2)-bf2f(h2)), (short)f2bf((e3)-bf2f(h3))}; \
    *(short4v*)&panH[sb] = ph; \
    *(short4v*)&panL[sb] = pl; }
    STG(0, v0.x, v1.x, v2.x, v3.x)
    STG(1, v0.y, v1.y, v2.y, v3.y)
    STG(2, v0.z, v1.z, v2.z, v3.z)
    STG(3, v0.w, v1.w, v2.w, v3.w)
#undef STG
    __syncthreads();
#pragma unroll
    for (int kk = 0; kk < 4; ++kk) {
      bf16x8 Bh[4], Bl[4];
#pragma unroll
      for (int tn = 0; tn < 4; ++tn) {
        int t = tn * 16 + cc;
        int g1 = ((t & 7) ^ (t >> 3));
        int sb = t * 128 + ((kk * 32 + 8 * g) ^ (g1 << 3));
        Bh[tn] = *(const bf16x8*)&panH[sb];
        Bl[tn] = *(const bf16x8*)&panL[sb];
      }
#pragma unroll
      for (int et = 0; et < 3; ++et) {
        size_t fidx = ((size_t)((eg0 + et) * 24 + (kc * 4 + kk))) * 128 + lane;
        union { int4v i; bf16x8 v; } ah, al;
        ah.i = Ab[fidx];
        al.i = Ab[fidx + 64];
#pragma unroll
        for (int tn = 0; tn < 4; ++tn) {
          acc[et][tn] = __builtin_amdgcn_mfma_f32_16x16x32_bf16(ah.v, Bh[tn], acc[et][tn], 0, 0, 0);
          acc[et][tn] = __builtin_amdgcn_mfma_f32_16x16x32_bf16(ah.v, Bl[tn], acc[et][tn], 0, 0, 0);
          acc[et][tn] = __builtin_amdgcn_mfma_f32_16x16x32_bf16(al.v, Bh[tn], acc[et][tn], 0, 0, 0);
        }
      }
    }
  }
  // epilogue: relu + dot(w2), reduce over e within block, atomicAdd partial logits
  float lg[4] = {0.f,0.f,0.f,0.f};
#pragma unroll
  for (int et = 0; et < 3; ++et) {
    int e = (eg0 + et) * 16 + 4 * g;
    float4 bb = *(const float4*)(b1 + e);
    float4 ww = *(const float4*)(w2 + e);
#pragma unroll
    for (int tn = 0; tn < 4; ++tn) {
      lg[tn] += fmaxf(acc[et][tn][0] + bb.x, 0.f) * ww.x;
      lg[tn] += fmaxf(acc[et][tn][1] + bb.y, 0.f) * ww.y;
      lg[tn] += fmaxf(acc[et][tn][2] + bb.z, 0.f) * ww.z;
      lg[tn] += fmaxf(acc[et][tn][3] + bb.w, 0.f) * ww.w;
    }
  }
#pragma unroll
  for (int tn = 0; tn < 4; ++tn) {
    lg[tn] += __shfl_xor(lg[tn], 16, 64);
    lg[tn] += __shfl_xor(lg[tn], 32, 64);
  }
  if (lane < 16) {
#pragma unroll
    for (int tn = 0; tn < 4; ++tn) red[wave][tn][lane] = lg[tn];
  }
  __syncthreads();
  if (tid < 64) {
    float v = 0.f;
#pragma unroll
    for (int w = 0; w < 8; ++w) v += red[w][tid >> 4][tid & 15];
    atomicAdd(&logit[b * N_ + n0 + tid], v);   // exactly 2 addends -> deterministic
  }
}

// ---------------- k_select: sigmoid + exact rank bijection + batch min/max + score write
__global__ __launch_bounds__(1024) void k_select(const float* __restrict__ logit,
                                                 const float* __restrict__ b2,
                                                 float* __restrict__ score,
                                                 int* __restrict__ rank,
                                                 float* __restrict__ mm) {
  __shared__ float s[N_];
  __shared__ float red[32];
  int tid = threadIdx.x;
  int b = blockIdx.x >> 2;
  int tg = blockIdx.x & 3;
  float b2v = b2[0];
  float sv0 = 1.f / (1.f + expf(-(logit[b * N_ + tid] + b2v)));
  s[tid] = sv0;
  __syncthreads();
  int token = tg * 256 + (tid >> 2);
  int jq = tid & 3;
  float si = s[token];
  int cnt = 0;
  int j0 = jq * 256;
  for (int j = j0; j < j0 + 256; j += 4) {
    float4 sj = *reinterpret_cast<const float4*>(&s[j]);
    cnt += (sj.x > si) || (sj.x == si && (j + 0) < token);
    cnt += (sj.y > si) || (sj.y == si && (j + 1) < token);
    cnt += (sj.z > si) || (sj.z == si && (j + 2) < token);
    cnt += (sj.w > si) || (sj.w == si && (j + 3) < token);
  }
  cnt += __shfl_xor(cnt, 1, 64);
  cnt += __shfl_xor(cnt, 2, 64);
  if (jq == 0) rank[b * N_ + token] = cnt;
  if (tg == 0) {
    score[b * N_ + tid] = sv0;
    float mn = sv0, mx = sv0;
#pragma unroll
    for (int off = 32; off > 0; off >>= 1) {
      mn = fminf(mn, __shfl_xor(mn, off, 64));
      mx = fmaxf(mx, __shfl_xor(mx, off, 64));
    }
    if ((tid & 63) == 0) { red[tid >> 6] = mn; red[16 + (tid >> 6)] = mx; }
    __syncthreads();
    if (tid == 0) {
      float a = red[0], c = red[16];
      for (int w = 1; w < 16; ++w) { a = fminf(a, red[w]); c = fmaxf(c, red[16 + w]); }
      mm[2 * b] = a; mm[2 * b + 1] = c;
    }
  }
}

// ---------------- k_gath: normalize*score + transpose + rank-compact (d-split, 3 blocks/CU)
// grid 1024: b(16) x nt(32 tokens-of-32) x dh(2 halves of 384)
__global__ __launch_bounds__(256) void k_gath(const float* __restrict__ xin,
                                              const float* __restrict__ score,
                                              const float* __restrict__ rs,
                                              const float* __restrict__ mu,
                                              const int* __restrict__ rank,
                                              short* __restrict__ gtT) {
  __shared__ float pan[32][389];
  __shared__ float ssc[32], ssh[32];
  __shared__ int rkv[32];
  int tid = threadIdx.x;
  int bid = blockIdx.x;
  int b = bid >> 6;
  int nt = (bid & 63) >> 1, dh = bid & 1;
  int n0 = nt * 32, d0 = dh * 384;
  int qt = tid & 7, qd = tid >> 3;
  const float* xb = xin + ((size_t)b * D_ + d0) * N_ + n0 + qt * 4;
#pragma unroll
  for (int it = 0; it < 12; ++it) {
    int d = it * 32 + qd;
    float4 v = *(const float4*)(xb + (size_t)d * N_);
    pan[qt*4+0][d] = v.x; pan[qt*4+1][d] = v.y; pan[qt*4+2][d] = v.z; pan[qt*4+3][d] = v.w;
  }
  if (tid < 32) {
    int n = b * N_ + n0 + tid;
    float sc = rs[n] * score[n];
    ssc[tid] = sc; ssh[tid] = -mu[n] * sc;
    rkv[tid] = rank[n];
  }
  __syncthreads();
  for (int t = 0; t < 32; ++t) {
    int rk = rkv[t];
    if (rk < TOPK_ && tid < 192) {
      float sc = ssc[t], sh = ssh[t];
      float u0 = pan[t][2*tid]   * sc + sh;
      float u1 = pan[t][2*tid+1] * sc + sh;
      ((uint*)(gtT + ((size_t)(b * TOPK_ + rk)) * D_ + d0))[tid] =
          (uint)f2bf(u0) | ((uint)f2bf(u1) << 16);
    }
  }
}

// ---------------- k_gemm2m: dselT[b][o][k] = db[o] + sum_d gtT[b][k][d]*Mt[d][o]
// grid 512: b(16) x kt(16 of 32 tokens) x oh(2 halves of 128 o). 256 thr = 4 waves.
__global__ __launch_bounds__(256, 4) void k_gemm2m(const short* __restrict__ gtT,
                                                   const short* __restrict__ mtA,
                                                   const float* __restrict__ db,
                                                   float* __restrict__ dselT) {
  __shared__ short pan[32 * 128];
  int tid = threadIdx.x;
  int wave = tid >> 6, lane = tid & 63;
  int g = lane >> 4, cc = lane & 15;
  int bid = blockIdx.x;
  int b = bid >> 5, kt = (bid & 31) >> 1, oh = bid & 1;
  int srow = tid >> 3, scol = (tid & 7) * 16;
  const short* gb = gtT + (size_t)(b * TOPK_ + kt * 32) * D_;
  f32x4 acc[2][2];
#pragma unroll
  for (int et = 0; et < 2; ++et)
#pragma unroll
    for (int tn = 0; tn < 2; ++tn) acc[et][tn] = (f32x4){0.f,0.f,0.f,0.f};
  const int4v* Am = (const int4v*)mtA;
  int sg1 = ((srow & 7) ^ (srow >> 3)) << 3;
  for (int kc = 0; kc < 6; ++kc) {
    int4v u0 = *(const int4v*)(gb + (size_t)srow * D_ + kc*128 + scol);
    int4v u1 = *(const int4v*)(gb + (size_t)srow * D_ + kc*128 + scol + 8);
    __syncthreads();
    *(int4v*)&pan[srow * 128 + (scol ^ sg1)] = u0;
    *(int4v*)&pan[srow * 128 + ((scol + 8) ^ sg1)] = u1;
    __syncthreads();
#pragma unroll
    for (int kk = 0; kk < 4; ++kk) {
      bf16x8 Bv[2];
#pragma unroll
      for (int tn = 0; tn < 2; ++tn) {
        int t = tn * 16 + cc;
        int g1 = ((t & 7) ^ (t >> 3));
        int sb = t * 128 + ((kk * 32 + 8 * g) ^ (g1 << 3));
        Bv[tn] = *(const bf16x8*)&pan[sb];
      }
#pragma unroll
      for (int et = 0; et < 2; ++et) {
        int og = oh * 8 + wave * 2 + et;
        size_t fidx = ((size_t)(og * 24 + (kc * 4 + kk))) * 64 + lane;
        union { int4v i; bf16x8 v; } av; av.i = Am[fidx];
#pragma unroll
        for (int tn = 0; tn < 2; ++tn)
          acc[et][tn] = __builtin_amdgcn_mfma_f32_16x16x32_bf16(av.v, Bv[tn], acc[et][tn], 0, 0, 0);
      }
    }
  }
#pragma unroll
  for (int et = 0; et < 2; ++et) {
    int og = oh * 8 + wave * 2 + et;
    int o0 = og * 16 + 4 * g;
#pragma unroll
    for (int r = 0; r < 4; ++r) {
      int o = o0 + r;
      float dbv = db[o];
      float* orow = dselT + ((size_t)(b * Z_ + o)) * TOPK_ + kt * 32 + cc;
      orow[0]  = acc[et][0][r] + dbv;
      orow[16] = acc[et][1][r] + dbv;
    }
  }
}

// ---------------- k_dec: dec[b][o][n] = selected ? dselT[b][o][rank[n]] : bg[o]
__global__ __launch_bounds__(256) void k_dec(const float* __restrict__ dselT,
                                             const float* __restrict__ bg,
                                             const int* __restrict__ rank,
                                             float* __restrict__ out) {
  __shared__ float row[TOPK_];
  __shared__ int rks[N_];
  int tid = threadIdx.x;
  int b = blockIdx.x >> 8;
  int o = blockIdx.x & 255;
  row[tid]       = dselT[((size_t)(b * Z_ + o)) * TOPK_ + tid];
  row[tid + 256] = dselT[((size_t)(b * Z_ + o)) * TOPK_ + tid + 256];
#pragma unroll
  for (int r = 0; r < 4; ++r) rks[r*256+tid] = rank[b * N_ + r*256 + tid];
  __syncthreads();
  float bgv = bg[o];
  float* orow = out + ((size_t)(b * Z_ + o)) * N_;
#pragma unroll
  for (int r = 0; r < 4; ++r) {
    int rk = rks[r*256+tid];
    orow[r*256+tid] = (rk < TOPK_) ? row[rk] : bgv;
  }
}

// ---------------- k_maps: binary_map + score_map (nearest upsample x16)
__global__ __launch_bounds__(128) void k_maps(const float* __restrict__ score,
                                              const int* __restrict__ rank,
                                              const float* __restrict__ mm,
                                              float* __restrict__ out) {
  int tid = threadIdx.x;
  int b = blockIdx.x >> 9;
  int ph = blockIdx.x & 511;
  float mn = mm[0], mx = mm[1];
#pragma unroll
  for (int w = 1; w < 16; ++w) { mn = fminf(mn, mm[2 * w]); mx = fmaxf(mx, mm[2 * w + 1]); }
  float inv = 1.f / fmaxf(mx - mn, EPS_);
  int pw0 = tid * 4;
  int cell = (ph >> 4) * HW_ + (pw0 >> 4);
  int rk = rank[b * N_ + cell];
  float bin = (rk < TOPK_) ? 1.f : 0.f;
  float sv = (score[b * N_ + cell] - mn) * inv;
  size_t base = (size_t)b * (512 * 512) + (size_t)ph * 512 + pw0;
  float4 bv = {bin, bin, bin, bin};
  float4 svv = {sv, sv, sv, sv};
  *reinterpret_cast<float4*>(out + 4194304 + base) = bv;
  *reinterpret_cast<float4*>(out + 8388608 + base) = svv;
}

extern "C" void kernel_launch(void* const* d_in, const int* in_sizes, int n_in,
                              void* d_out, int out_size, void* d_ws, size_t ws_size,
                              hipStream_t stream) {
  const float* xin = (const float*)d_in[0];
  const float* w1  = (const float*)d_in[1];
  const float* b1  = (const float*)d_in[2];
  const float* w2  = (const float*)d_in[3];
  const float* b2  = (const float*)d_in[4];
  const float* wp  = (const float*)d_in[5];
  const float* bp  = (const float*)d_in[6];
  const float* mtk = (const float*)d_in[7];
  const float* cw  = (const float*)d_in[8];
  const float* cb  = (const float*)d_in[9];
  float* out = (float*)d_out;

  short* wA    = (short*)d_ws;                // 1,179,648 shorts
  short* mtA   = wA + 1179648;                // 196,608 shorts
  short* gtT   = mtA + 196608;                // 6,291,456 shorts
  float* cwT   = (float*)(gtT + 6291456);     // 65,536 floats
  float* db    = cwT + 65536;
  float* bg    = db + 256;
  float* logit = bg + 256;                    // 16,384
  float* score = logit + 16384;               // 16,384
  float* rs    = score + 16384;               // 16,384
  float* mu    = rs + 16384;                  // 16,384
  float* mm    = mu + 16384;                  // 32
  int*   rank  = (int*)(mm + 32);             // 16,384
  float* dselT = (float*)(rank + 16384);      // 2,097,152 floats

  k_zero      <<<dim3(16),   dim3(1024), 0, stream>>>(logit);
  k_db        <<<dim3(256),  dim3(256),  0, stream>>>(cw, cb, bp, mtk, db, bg);
  k_cwT       <<<dim3(64),   dim3(256),  0, stream>>>(cw, cwT);
  k_w1pack    <<<dim3(1152), dim3(64),   0, stream>>>(w1, wA);
  k_mtpA      <<<dim3(96),   dim3(256),  0, stream>>>(wp, cwT, mtA);
  k_stats     <<<dim3(256),  dim3(256),  0, stream>>>(xin, rs, mu);
  k_score_mfma<<<dim3(512),  dim3(512),  0, stream>>>(xin, wA, b1, w2, logit);
  k_select    <<<dim3(64),   dim3(1024), 0, stream>>>(logit, b2, score, rank, mm);
  k_gath      <<<dim3(1024), dim3(256),  0, stream>>>(xin, score, rs, mu, rank, gtT);
  k_gemm2m    <<<dim3(512),  dim3(256),  0, stream>>>(gtT, mtA, db, dselT);
  k_dec       <<<dim3(4096), dim3(256),  0, stream>>>(dselT, bg, rank, out);
  k_maps      <<<dim3(8192), dim3(128),  0, stream>>>(score, rank, mm, out);
}

// Round 6
// 222.063 us; speedup vs baseline: 1.3790x; 1.3790x over previous
//
#include <hip/hip_runtime.h>
#include <hip/hip_bf16.h>
#include <math.h>

#define B_ 16
#define D_ 768
#define N_ 1024
#define Z_ 256
#define TOPK_ 512
#define HW_ 32
#define EPS_ 1e-5f

typedef unsigned int uint;
typedef unsigned short ushort;
typedef __attribute__((ext_vector_type(4))) short short4v;
typedef __attribute__((ext_vector_type(8))) short bf16x8;
typedef __attribute__((ext_vector_type(4))) float f32x4;
typedef __attribute__((ext_vector_type(4))) int int4v;

__device__ __forceinline__ ushort f2bf(float v) {
  uint b = __float_as_uint(v);
  b += 0x7FFFu + ((b >> 16) & 1u);
  return (ushort)(b >> 16);
}
__device__ __forceinline__ float bf2f(ushort h) { return __uint_as_float(((uint)h) << 16); }
__device__ __forceinline__ int pk2(ushort a, ushort b) { return (int)((uint)a | ((uint)b << 16)); }

// ---------------- k_db: db[o] = cb[o]+cw[o,:]@bp ; bg[o] = cb[o]+cw[o,:]@mtk
__global__ __launch_bounds__(256) void k_db(const float* __restrict__ cw,
                                            const float* __restrict__ cb,
                                            const float* __restrict__ bp,
                                            const float* __restrict__ mtk,
                                            float* __restrict__ db,
                                            float* __restrict__ bg) {
  __shared__ float s1[4], s2[4];
  int o = blockIdx.x, tid = threadIdx.x;
  float c = cw[o * Z_ + tid];
  float a1 = c * bp[tid], a2 = c * mtk[tid];
#pragma unroll
  for (int m = 32; m > 0; m >>= 1) { a1 += __shfl_xor(a1, m, 64); a2 += __shfl_xor(a2, m, 64); }
  if ((tid & 63) == 0) { s1[tid >> 6] = a1; s2[tid >> 6] = a2; }
  __syncthreads();
  if (tid == 0) {
    db[o] = cb[o] + s1[0] + s1[1] + s1[2] + s1[3];
    bg[o] = cb[o] + s2[0] + s2[1] + s2[2] + s2[3];
  }
}

// ---------------- k_cwT: transpose conv_w (256x256) via 32x32 LDS tiles
__global__ __launch_bounds__(256) void k_cwT(const float* __restrict__ cw,
                                             float* __restrict__ cwT) {
  __shared__ float tile[32][33];
  int bx = blockIdx.x & 7, by = blockIdx.x >> 3;
  int tid = threadIdx.x;
#pragma unroll
  for (int it = 0; it < 4; ++it) {
    int idx = it * 256 + tid, r = idx >> 5, c = idx & 31;
    tile[r][c] = cw[(size_t)(by * 32 + r) * Z_ + bx * 32 + c];
  }
  __syncthreads();
#pragma unroll
  for (int it = 0; it < 4; ++it) {
    int idx = it * 256 + tid, r = idx >> 5, c = idx & 31;
    cwT[(size_t)(bx * 32 + r) * Z_ + by * 32 + c] = tile[c][r];
  }
}

// ---------------- k_w1pack: A-fragments of w1^T, hi/lo split bf16 (contiguous k)
__global__ __launch_bounds__(64) void k_w1pack(const float* __restrict__ w1,
                                               short* __restrict__ wA) {
  int lane = threadIdx.x;
  int f = blockIdx.x;             // 48*24 = 1152
  int eg = f / 24, kkg = f % 24;
  int e = eg * 16 + (lane & 15);
  int d0 = kkg * 32 + 8 * (lane >> 4);
  ushort hh[8], ll[8];
#pragma unroll
  for (int j = 0; j < 8; ++j) {
    float v = w1[(size_t)(d0 + j) * D_ + e];
    hh[j] = f2bf(v);
    ll[j] = f2bf(v - bf2f(hh[j]));
  }
  int4v ph = {pk2(hh[0],hh[1]), pk2(hh[2],hh[3]), pk2(hh[4],hh[5]), pk2(hh[6],hh[7])};
  int4v pl = {pk2(ll[0],ll[1]), pk2(ll[2],ll[3]), pk2(ll[4],ll[5]), pk2(ll[6],ll[7])};
  int4v* W = (int4v*)wA;
  W[(size_t)f * 128 + lane] = ph;
  W[(size_t)f * 128 + 64 + lane] = pl;
}

// ---------------- k_mtpA: Mt[d][o] = sum_z wp[d][z]*cwT[z][o], written as packed A-frags
__global__ __launch_bounds__(256) void k_mtpA(const float* __restrict__ wp,
                                              const float* __restrict__ cwT,
                                              short* __restrict__ mtA) {
  int o = threadIdx.x;
  int d0 = blockIdx.x * 8;
  int kkg = blockIdx.x >> 2, g = blockIdx.x & 3;
  float acc[8] = {0.f,0.f,0.f,0.f,0.f,0.f,0.f,0.f};
  for (int z = 0; z < Z_; ++z) {
    float c = cwT[(size_t)z * Z_ + o];
#pragma unroll
    for (int j = 0; j < 8; ++j) acc[j] += wp[(size_t)(d0 + j) * Z_ + z] * c;
  }
  int og = o >> 4, lane = (o & 15) + 16 * g;
  int4v p = {pk2(f2bf(acc[0]),f2bf(acc[1])), pk2(f2bf(acc[2]),f2bf(acc[3])),
             pk2(f2bf(acc[4]),f2bf(acc[5])), pk2(f2bf(acc[6]),f2bf(acc[7]))};
  ((int4v*)mtA)[(size_t)(og * 24 + kkg) * 64 + lane] = p;
}

// ---------------- k_score_mfma: FUSED score(MFMA split-bf16) + LN stats + gtT_all write
// grid 256 (b x 16 tiles of 64 tokens), 512 thr = 8 waves; wave owns 96 e's (6 et) x 64 tokens (4 tn).
__global__ __launch_bounds__(512, 2) void k_score_mfma(const float* __restrict__ xin,
                                                       const short* __restrict__ wA,
                                                       const float* __restrict__ b1,
                                                       const float* __restrict__ w2,
                                                       const float* __restrict__ b2,
                                                       float* __restrict__ score,
                                                       short* __restrict__ gtT) {
  __shared__ short panH[64 * 768];           // 96 KB, full x tile (bf16 hi), swizzled rows
  __shared__ short panL[64 * 128];           // 16 KB, lo part, per-chunk
  __shared__ float redS[8][16][4], redQ[8][16][4];
  __shared__ float redL[8][4][16];
  __shared__ float ssc[64], ssh[64];
  int tid = threadIdx.x;
  int wave = tid >> 6, lane = tid & 63;
  int g = lane >> 4, cc = lane & 15;
  int b = blockIdx.x >> 4;
  int n0 = (blockIdx.x & 15) * 64;
  const float* xb = xin + (size_t)b * D_ * N_ + n0;
  int qt = tid & 15, qd = tid >> 4;
  int t0 = qt * 4, dl0 = qd * 4;
  float ss[4] = {0.f,0.f,0.f,0.f}, sq[4] = {0.f,0.f,0.f,0.f};
  f32x4 acc[6][4];
#pragma unroll
  for (int et = 0; et < 6; ++et)
#pragma unroll
    for (int tn = 0; tn < 4; ++tn) acc[et][tn] = (f32x4){0.f,0.f,0.f,0.f};
  const int4v* Ab = (const int4v*)wA;
  int eg0 = wave * 6;
  for (int kc = 0; kc < 6; ++kc) {
    float4 v0 = *(const float4*)(xb + (size_t)(kc*128 + dl0 + 0) * N_ + t0);
    float4 v1 = *(const float4*)(xb + (size_t)(kc*128 + dl0 + 1) * N_ + t0);
    float4 v2 = *(const float4*)(xb + (size_t)(kc*128 + dl0 + 2) * N_ + t0);
    float4 v3 = *(const float4*)(xb + (size_t)(kc*128 + dl0 + 3) * N_ + t0);
    // stats accumulate (token t0+j gets component j of each v)
    ss[0] += v0.x+v1.x+v2.x+v3.x; sq[0] += v0.x*v0.x+v1.x*v1.x+v2.x*v2.x+v3.x*v3.x;
    ss[1] += v0.y+v1.y+v2.y+v3.y; sq[1] += v0.y*v0.y+v1.y*v1.y+v2.y*v2.y+v3.y*v3.y;
    ss[2] += v0.z+v1.z+v2.z+v3.z; sq[2] += v0.z*v0.z+v1.z*v1.z+v2.z*v2.z+v3.z*v3.z;
    ss[3] += v0.w+v1.w+v2.w+v3.w; sq[3] += v0.w*v0.w+v1.w*v1.w+v2.w*v2.w+v3.w*v3.w;
    __syncthreads();   // previous chunk's MFMA (panL) done before overwrite
#define STG(j, e0, e1, e2, e3) { \
    int t = t0 + (j); \
    int g1 = ((t & 7) ^ (t >> 3)); \
    int sbH = t * 768 + ((kc*128 + dl0) ^ (g1 << 3)); \
    int sbL = t * 128 + (dl0 ^ (g1 << 3)); \
    ushort h0 = f2bf(e0), h1 = f2bf(e1), h2 = f2bf(e2), h3 = f2bf(e3); \
    short4v ph = {(short)h0,(short)h1,(short)h2,(short)h3}; \
    short4v pl = {(short)f2bf((e0)-bf2f(h0)), (short)f2bf((e1)-bf2f(h1)), \
                  (short)f2bf((e2)-bf2f(h2)), (short)f2bf((e3)-bf2f(h3))}; \
    *(short4v*)&panH[sbH] = ph; \
    *(short4v*)&panL[sbL] = pl; }
    STG(0, v0.x, v1.x, v2.x, v3.x)
    STG(1, v0.y, v1.y, v2.y, v3.y)
    STG(2, v0.z, v1.z, v2.z, v3.z)
    STG(3, v0.w, v1.w, v2.w, v3.w)
#undef STG
    __syncthreads();
#pragma unroll
    for (int kk = 0; kk < 4; ++kk) {
      bf16x8 Bh[4], Bl[4];
#pragma unroll
      for (int tn = 0; tn < 4; ++tn) {
        int t = tn * 16 + cc;
        int g1 = ((t & 7) ^ (t >> 3));
        Bh[tn] = *(const bf16x8*)&panH[t * 768 + ((kc*128 + kk*32 + 8*g) ^ (g1 << 3))];
        Bl[tn] = *(const bf16x8*)&panL[t * 128 + ((kk*32 + 8*g) ^ (g1 << 3))];
      }
#pragma unroll
      for (int et = 0; et < 6; ++et) {
        size_t fidx = ((size_t)((eg0 + et) * 24 + (kc * 4 + kk))) * 128 + lane;
        union { int4v i; bf16x8 v; } ah, al;
        ah.i = Ab[fidx];
        al.i = Ab[fidx + 64];
#pragma unroll
        for (int tn = 0; tn < 4; ++tn) {
          acc[et][tn] = __builtin_amdgcn_mfma_f32_16x16x32_bf16(ah.v, Bh[tn], acc[et][tn], 0, 0, 0);
          acc[et][tn] = __builtin_amdgcn_mfma_f32_16x16x32_bf16(ah.v, Bl[tn], acc[et][tn], 0, 0, 0);
          acc[et][tn] = __builtin_amdgcn_mfma_f32_16x16x32_bf16(al.v, Bh[tn], acc[et][tn], 0, 0, 0);
        }
      }
    }
  }
  // ---- stats wave-reduce (threads sharing qt: lane stride 16)
#pragma unroll
  for (int j = 0; j < 4; ++j) {
    ss[j] += __shfl_xor(ss[j], 16, 64); sq[j] += __shfl_xor(sq[j], 16, 64);
    ss[j] += __shfl_xor(ss[j], 32, 64); sq[j] += __shfl_xor(sq[j], 32, 64);
  }
  if (lane < 16) {
#pragma unroll
    for (int j = 0; j < 4; ++j) { redS[wave][lane][j] = ss[j]; redQ[wave][lane][j] = sq[j]; }
  }
  // ---- logits: relu + dot(w2), reduce over e
  float lg[4] = {0.f,0.f,0.f,0.f};
#pragma unroll
  for (int et = 0; et < 6; ++et) {
    int e = (eg0 + et) * 16 + 4 * g;
    float4 bb = *(const float4*)(b1 + e);
    float4 ww = *(const float4*)(w2 + e);
#pragma unroll
    for (int tn = 0; tn < 4; ++tn) {
      lg[tn] += fmaxf(acc[et][tn][0] + bb.x, 0.f) * ww.x;
      lg[tn] += fmaxf(acc[et][tn][1] + bb.y, 0.f) * ww.y;
      lg[tn] += fmaxf(acc[et][tn][2] + bb.z, 0.f) * ww.z;
      lg[tn] += fmaxf(acc[et][tn][3] + bb.w, 0.f) * ww.w;
    }
  }
#pragma unroll
  for (int tn = 0; tn < 4; ++tn) {
    lg[tn] += __shfl_xor(lg[tn], 16, 64);
    lg[tn] += __shfl_xor(lg[tn], 32, 64);
  }
  if (lane < 16) {
#pragma unroll
    for (int tn = 0; tn < 4; ++tn) redL[wave][tn][lane] = lg[tn];
  }
  __syncthreads();
  if (tid < 64) {
    int t = tid;
    float S = 0.f, Q = 0.f, L = 0.f;
#pragma unroll
    for (int w = 0; w < 8; ++w) {
      S += redS[w][t >> 2][t & 3];
      Q += redQ[w][t >> 2][t & 3];
      L += redL[w][t >> 4][t & 15];
    }
    float mu = S * (1.f / D_);
    float var = Q * (1.f / D_) - mu * mu;
    float rs = rsqrtf(var + EPS_);
    float sv = 1.f / (1.f + expf(-(L + b2[0])));
    score[b * N_ + n0 + t] = sv;
    float sc = rs * sv;
    ssc[t] = sc; ssh[t] = -mu * sc;
  }
  __syncthreads();
  // ---- gtT_all write: token t = tid>>3, d-segment seg = tid&7 (96 d's each)
  {
    int t = tid >> 3, seg = tid & 7;
    int g1 = ((t & 7) ^ (t >> 3));
    float sc = ssc[t], sh = ssh[t];
    uint* gout = (uint*)(gtT + ((size_t)(b * N_ + n0 + t)) * D_ + seg * 96);
#pragma unroll
    for (int i = 0; i < 12; ++i) {
      int d8 = seg * 96 + i * 8;
      bf16x8 hv = *(const bf16x8*)&panH[t * 768 + (d8 ^ (g1 << 3))];
      uint u0 = pk2(f2bf(bf2f((ushort)hv[0])*sc+sh), f2bf(bf2f((ushort)hv[1])*sc+sh));
      uint u1 = pk2(f2bf(bf2f((ushort)hv[2])*sc+sh), f2bf(bf2f((ushort)hv[3])*sc+sh));
      uint u2 = pk2(f2bf(bf2f((ushort)hv[4])*sc+sh), f2bf(bf2f((ushort)hv[5])*sc+sh));
      uint u3 = pk2(f2bf(bf2f((ushort)hv[6])*sc+sh), f2bf(bf2f((ushort)hv[7])*sc+sh));
      int4v pv = {(int)u0, (int)u1, (int)u2, (int)u3};
      *(int4v*)(gout + i * 4) = pv;
    }
  }
}

// ---------------- k_select: exact rank (stable argsort(-s) semantics) + batch min/max
__global__ __launch_bounds__(1024) void k_select(const float* __restrict__ score,
                                                 int* __restrict__ rank,
                                                 float* __restrict__ mm) {
  __shared__ float s[N_];
  __shared__ float red[32];
  int tid = threadIdx.x;
  int b = blockIdx.x >> 2;
  int tg = blockIdx.x & 3;
  s[tid] = score[b * N_ + tid];
  __syncthreads();
  int token = tg * 256 + (tid >> 2);
  int jq = tid & 3;
  float si = s[token];
  int cnt = 0;
  int j0 = jq * 256;
  for (int j = j0; j < j0 + 256; j += 4) {
    float4 sj = *reinterpret_cast<const float4*>(&s[j]);
    cnt += (sj.x > si) || (sj.x == si && (j + 0) < token);
    cnt += (sj.y > si) || (sj.y == si && (j + 1) < token);
    cnt += (sj.z > si) || (sj.z == si && (j + 2) < token);
    cnt += (sj.w > si) || (sj.w == si && (j + 3) < token);
  }
  cnt += __shfl_xor(cnt, 1, 64);
  cnt += __shfl_xor(cnt, 2, 64);
  if (jq == 0) rank[b * N_ + token] = cnt;
  if (tg == 0) {
    float v = s[tid];
    float mn = v, mx = v;
#pragma unroll
    for (int off = 32; off > 0; off >>= 1) {
      mn = fminf(mn, __shfl_xor(mn, off, 64));
      mx = fmaxf(mx, __shfl_xor(mx, off, 64));
    }
    if ((tid & 63) == 0) { red[tid >> 6] = mn; red[16 + (tid >> 6)] = mx; }
    __syncthreads();
    if (tid == 0) {
      float a = red[0], c = red[16];
      for (int w = 1; w < 16; ++w) { a = fminf(a, red[w]); c = fmaxf(c, red[16 + w]); }
      mm[2 * b] = a; mm[2 * b + 1] = c;
    }
  }
}

// ---------------- k_gemm2dec: dec[b][o][n] = sel ? db[o]+sum_d gtT[b][n][d]*Mt[d][o] : bg[o]
// grid 1024: b(16) x kt(32 tiles of 32 tokens) x oh(2 halves of 128 o). 256 thr = 4 waves.
__global__ __launch_bounds__(256, 4) void k_gemm2dec(const short* __restrict__ gtT,
                                                     const short* __restrict__ mtA,
                                                     const float* __restrict__ db,
                                                     const float* __restrict__ bg,
                                                     const int* __restrict__ rank,
                                                     float* __restrict__ out) {
  __shared__ short pan[32 * 128];
  __shared__ int rks[32];
  int tid = threadIdx.x;
  int wave = tid >> 6, lane = tid & 63;
  int g = lane >> 4, cc = lane & 15;
  int bid = blockIdx.x;
  int b = bid >> 6, kt = (bid & 63) >> 1, oh = bid & 1;
  if (tid < 32) rks[tid] = rank[b * N_ + kt * 32 + tid];
  int srow = tid >> 3, scol = (tid & 7) * 16;
  const short* gb = gtT + (size_t)(b * N_ + kt * 32) * D_;
  f32x4 acc[2][2];
#pragma unroll
  for (int et = 0; et < 2; ++et)
#pragma unroll
    for (int tn = 0; tn < 2; ++tn) acc[et][tn] = (f32x4){0.f,0.f,0.f,0.f};
  const int4v* Am = (const int4v*)mtA;
  int sg1 = ((srow & 7) ^ (srow >> 3)) << 3;
  for (int kc = 0; kc < 6; ++kc) {
    int4v u0 = *(const int4v*)(gb + (size_t)srow * D_ + kc*128 + scol);
    int4v u1 = *(const int4v*)(gb + (size_t)srow * D_ + kc*128 + scol + 8);
    __syncthreads();
    *(int4v*)&pan[srow * 128 + (scol ^ sg1)] = u0;
    *(int4v*)&pan[srow * 128 + ((scol + 8) ^ sg1)] = u1;
    __syncthreads();
#pragma unroll
    for (int kk = 0; kk < 4; ++kk) {
      bf16x8 Bv[2];
#pragma unroll
      for (int tn = 0; tn < 2; ++tn) {
        int t = tn * 16 + cc;
        int g1 = ((t & 7) ^ (t >> 3));
        Bv[tn] = *(const bf16x8*)&pan[t * 128 + ((kk * 32 + 8 * g) ^ (g1 << 3))];
      }
#pragma unroll
      for (int et = 0; et < 2; ++et) {
        int og = oh * 8 + wave * 2 + et;
        size_t fidx = ((size_t)(og * 24 + (kc * 4 + kk))) * 64 + lane;
        union { int4v i; bf16x8 v; } av; av.i = Am[fidx];
#pragma unroll
        for (int tn = 0; tn < 2; ++tn)
          acc[et][tn] = __builtin_amdgcn_mfma_f32_16x16x32_bf16(av.v, Bv[tn], acc[et][tn], 0, 0, 0);
      }
    }
  }
  int rk0 = rks[cc], rk1 = rks[cc + 16];
#pragma unroll
  for (int et = 0; et < 2; ++et) {
    int og = oh * 8 + wave * 2 + et;
    int o0 = og * 16 + 4 * g;
#pragma unroll
    for (int r = 0; r < 4; ++r) {
      int o = o0 + r;
      float dbv = db[o], bgv = bg[o];
      float* orow = out + ((size_t)(b * Z_ + o)) * N_ + kt * 32 + cc;
      orow[0]  = (rk0 < TOPK_) ? acc[et][0][r] + dbv : bgv;
      orow[16] = (rk1 < TOPK_) ? acc[et][1][r] + dbv : bgv;
    }
  }
}

// ---------------- k_maps: binary_map + score_map (nearest upsample x16)
__global__ __launch_bounds__(128) void k_maps(const float* __restrict__ score,
                                              const int* __restrict__ rank,
                                              const float* __restrict__ mm,
                                              float* __restrict__ out) {
  int tid = threadIdx.x;
  int b = blockIdx.x >> 9;
  int ph = blockIdx.x & 511;
  float mn = mm[0], mx = mm[1];
#pragma unroll
  for (int w = 1; w < 16; ++w) { mn = fminf(mn, mm[2 * w]); mx = fmaxf(mx, mm[2 * w + 1]); }
  float inv = 1.f / fmaxf(mx - mn, EPS_);
  int pw0 = tid * 4;
  int cell = (ph >> 4) * HW_ + (pw0 >> 4);
  int rk = rank[b * N_ + cell];
  float bin = (rk < TOPK_) ? 1.f : 0.f;
  float sv = (score[b * N_ + cell] - mn) * inv;
  size_t base = (size_t)b * (512 * 512) + (size_t)ph * 512 + pw0;
  float4 bv = {bin, bin, bin, bin};
  float4 svv = {sv, sv, sv, sv};
  *reinterpret_cast<float4*>(out + 4194304 + base) = bv;
  *reinterpret_cast<float4*>(out + 8388608 + base) = svv;
}

extern "C" void kernel_launch(void* const* d_in, const int* in_sizes, int n_in,
                              void* d_out, int out_size, void* d_ws, size_t ws_size,
                              hipStream_t stream) {
  const float* xin = (const float*)d_in[0];
  const float* w1  = (const float*)d_in[1];
  const float* b1  = (const float*)d_in[2];
  const float* w2  = (const float*)d_in[3];
  const float* b2  = (const float*)d_in[4];
  const float* wp  = (const float*)d_in[5];
  const float* bp  = (const float*)d_in[6];
  const float* mtk = (const float*)d_in[7];
  const float* cw  = (const float*)d_in[8];
  const float* cb  = (const float*)d_in[9];
  float* out = (float*)d_out;

  short* wA    = (short*)d_ws;                // 1,179,648 shorts
  short* mtA   = wA + 1179648;                // 196,608 shorts
  short* gtT   = mtA + 196608;                // 12,582,912 shorts (all tokens, token-major)
  float* cwT   = (float*)(gtT + 12582912);    // 65,536 floats
  float* db    = cwT + 65536;                 // 256
  float* bg    = db + 256;                    // 256
  float* score = bg + 256;                    // 16,384
  float* mm    = score + 16384;               // 32
  int*   rank  = (int*)(mm + 32);             // 16,384
  // total ~28.5 MB

  k_db        <<<dim3(256),  dim3(256),  0, stream>>>(cw, cb, bp, mtk, db, bg);
  k_cwT       <<<dim3(64),   dim3(256),  0, stream>>>(cw, cwT);
  k_mtpA      <<<dim3(96),   dim3(256),  0, stream>>>(wp, cwT, mtA);
  k_w1pack    <<<dim3(1152), dim3(64),   0, stream>>>(w1, wA);
  k_score_mfma<<<dim3(256),  dim3(512),  0, stream>>>(xin, wA, b1, w2, b2, score, gtT);
  k_select    <<<dim3(64),   dim3(1024), 0, stream>>>(score, rank, mm);
  k_gemm2dec  <<<dim3(1024), dim3(256),  0, stream>>>(gtT, mtA, db, bg, rank, out);
  k_maps      <<<dim3(8192), dim3(128),  0, stream>>>(score, rank, mm, out);
}